// Round 10
// baseline (971.859 us; speedup 1.0000x reference)
//
#include <hip/hip_runtime.h>

#define Bsz 256
#define Tsz 512
#define Isz 64
#define Hsz 128
#define G4  512   // 4*H

typedef _Float16 f16;
typedef _Float16 f16x8 __attribute__((ext_vector_type(8)));
typedef _Float16 f16x4 __attribute__((ext_vector_type(4)));
typedef float floatx4 __attribute__((ext_vector_type(4)));

#define MFMA(A, B, C) __builtin_amdgcn_mfma_f32_16x16x32_f16((A), (B), (C), 0, 0, 0)

// LDS-only barrier: drains lgkmcnt but NOT vmcnt -> in-loop global traffic
// (prefetch loads, hs stores) never serializes a step.
__device__ __forceinline__ void lds_barrier() {
  asm volatile("s_waitcnt lgkmcnt(0)\n\ts_barrier" ::: "memory");
}

__device__ __forceinline__ float sigm_f(float x) {
  float e = __builtin_amdgcn_exp2f(x * -1.4426950408889634f);
  return __builtin_amdgcn_rcpf(1.0f + e);
}
__device__ __forceinline__ float tanh_f(float x) {
  float e = __builtin_amdgcn_exp2f(x * -2.8853900817779268f);
  return 2.0f * __builtin_amdgcn_rcpf(1.0f + e) - 1.0f;
}

__device__ __forceinline__ f16x8 load_wfrag(const float* __restrict__ W, int n, int stride, int k) {
  const float* p = W + (size_t)n * stride + k;
  float4 a = *(const float4*)p;
  float4 b = *(const float4*)(p + 4);
  f16x8 r;
  r[0] = (f16)a.x; r[1] = (f16)a.y; r[2] = (f16)a.z; r[3] = (f16)a.w;
  r[4] = (f16)b.x; r[5] = (f16)b.y; r[6] = (f16)b.z; r[7] = (f16)b.w;
  return r;
}

// pack two float4 (8 f32) -> f16x8 (VALU only; used to defer cvt off the load)
__device__ __forceinline__ f16x8 pack_frag(const float4& a, const float4& b) {
  f16x8 r;
  r[0] = (f16)a.x; r[1] = (f16)a.y; r[2] = (f16)a.z; r[3] = (f16)a.w;
  r[4] = (f16)b.x; r[5] = (f16)b.y; r[6] = (f16)b.z; r[7] = (f16)b.w;
  return r;
}

// Shared-denominator LSTM cell: 5 exp2 + 2 rcp.
__device__ __forceinline__ float lstm_cell(float ipre, float fpre, float gpre,
                                           float opre, float& c) {
  const float ei = __builtin_amdgcn_exp2f(fminf(ipre * -1.4426950408889634f, 30.f));
  const float ef = __builtin_amdgcn_exp2f(fminf(fpre * -1.4426950408889634f, 30.f));
  const float eg = __builtin_amdgcn_exp2f(fminf(gpre * -2.8853900817779268f, 30.f));
  const float eo = __builtin_amdgcn_exp2f(fminf(opre * -1.4426950408889634f, 30.f));
  const float pf1 = 1.f + ef;
  const float P = (1.f + ei) * (1.f + eg);
  const float num = fmaf(c, P, pf1 * (1.f - eg));
  const float cn = num * __builtin_amdgcn_rcpf(pf1 * P);
  c = cn;
  const float ec = __builtin_amdgcn_exp2f(fminf(cn * -2.8853900817779268f, 30.f));
  return (1.f - ec) * __builtin_amdgcn_rcpf((1.f + eo) * (1.f + ec));
}

// Extract acc[r=q] (row 4q+q == lane's batch) with 3 cndmask.
__device__ __forceinline__ float sel_q(const floatx4& a, bool qb0, bool qb1) {
  const float a01 = qb0 ? a[1] : a[0];
  const float a23 = qb0 ? a[3] : a[2];
  return qb1 ? a23 : a01;
}

// Layer-0 BiLSTM scan, 4 batches/block, 1 cell/lane. 128 blocks (0..63 fwd,
// 64..127 rev) x 512 thr. fp32 x read directly (cvt kernel fused away): ring
// slots hold raw float4s, packed to f16 at USE time (4 steps after load -> no
// same-step vmcnt). Recurrent MFMA split into two 2-deep chains.
__global__ __launch_bounds__(512, 1) void lstm_scan_l0(
    const float* __restrict__ xf32,
    const float* __restrict__ Wih_f, const float* __restrict__ Whh_f,
    const float* __restrict__ bih_f, const float* __restrict__ bhh_f,
    const float* __restrict__ Wih_r, const float* __restrict__ Whh_r,
    const float* __restrict__ bih_r, const float* __restrict__ bhh_r,
    f16* __restrict__ hs) {
  const int dir = ((int)blockIdx.x >= 64) ? 1 : 0;
  const int bb = ((int)blockIdx.x & 63) * 4;
  const float* __restrict__ Wih = dir ? Wih_r : Wih_f;
  const float* __restrict__ Whh = dir ? Whh_r : Whh_f;
  const float* __restrict__ bih = dir ? bih_r : bih_f;
  const float* __restrict__ bhh = dir ? bhh_r : bhh_f;

  __shared__ __align__(16) f16 hq[2][4][144];

  const int tid = threadIdx.x;
  const int lane = tid & 63;
  const int w = tid >> 6;
  const int l15 = lane & 15;
  const int q = lane >> 4;
  const int jcol = w * 16 + l15;
  const int mrow = l15 & 3;
  const bool qb0 = (q & 1) != 0;
  const bool qb1 = (q & 2) != 0;

  f16x8 wi[4][2], wh[4][4];
  float bsum[4];
#pragma unroll
  for (int g = 0; g < 4; ++g) {
    const int n = g * 128 + jcol;
#pragma unroll
    for (int kt = 0; kt < 2; ++kt) wi[g][kt] = load_wfrag(Wih, n, Isz, kt * 32 + q * 8);
#pragma unroll
    for (int kt = 0; kt < 4; ++kt) wh[g][kt] = load_wfrag(Whh, n, Hsz, kt * 32 + q * 8);
    bsum[g] = bih[n] + bhh[n];
  }

  for (int i = tid; i < 2 * 4 * 144; i += 512) (&hq[0][0][0])[i] = (f16)0.f;

  float cst = 0.f;
  const int t0 = dir ? (Tsz - 1) : 0;
  const int dt = dir ? -1 : 1;
  const ptrdiff_t xstep = (ptrdiff_t)dt * Isz;

  const float* xp = xf32 + ((size_t)(bb + mrow) * Tsz + t0) * Isz + q * 8;

  // prime gacc = bias + xproj(t0)
  floatx4 gacc[4];
  {
    f16x8 x0 = load_wfrag(xp, 0, 0, 0);
    f16x8 x1 = load_wfrag(xp + 32, 0, 0, 0);
#pragma unroll
    for (int g = 0; g < 4; ++g) {
      gacc[g][0] = bsum[g]; gacc[g][1] = bsum[g];
      gacc[g][2] = bsum[g]; gacc[g][3] = bsum[g];
      gacc[g] = MFMA(x0, wi[g][0], gacc[g]);
      gacc[g] = MFMA(x1, wi[g][1], gacc[g]);
    }
  }

  // ring slot s holds raw f32 x(t+1) for steps t == s (mod 4); primed x(1..4)
  float4 rA0[4], rA1[4], rB0[4], rB1[4];
#pragma unroll
  for (int s = 0; s < 4; ++s) {
    const float* p = xp + (ptrdiff_t)(s + 1) * xstep;
    rA0[s] = *(const float4*)p;       rA1[s] = *(const float4*)(p + 4);
    rB0[s] = *(const float4*)(p + 32); rB1[s] = *(const float4*)(p + 36);
  }
  const float* xpn = xp + 5 * xstep;   // next load: x(t+5) at step t

  f16* hsp = hs + ((size_t)(bb + q) * Tsz + t0) * 256 + dir * 128 + jcol;
  const ptrdiff_t hstep = (ptrdiff_t)dt * 256;

  __syncthreads();

  auto step = [&](int t, float4& a0, float4& a1, float4& b0, float4& b1) {
    f16x8 ah[4];
#pragma unroll
    for (int kt = 0; kt < 4; ++kt)
      ah[kt] = *(const f16x8*)(&hq[t & 1][mrow][kt * 32 + q * 8]);

    // two 2-deep chains: gacc (kt 0,1) and acc2 (kt 2,3), combined at sel
    floatx4 acc2[4];
#pragma unroll
    for (int g = 0; g < 4; ++g) {
      floatx4 z; z[0] = 0.f; z[1] = 0.f; z[2] = 0.f; z[3] = 0.f;
      acc2[g] = MFMA(ah[2], wh[g][2], z);
      acc2[g] = MFMA(ah[3], wh[g][3], acc2[g]);
      gacc[g] = MFMA(ah[0], wh[g][0], gacc[g]);
      gacc[g] = MFMA(ah[1], wh[g][1], gacc[g]);
    }

    const float pi = sel_q(gacc[0], qb0, qb1) + sel_q(acc2[0], qb0, qb1);
    const float pf = sel_q(gacc[1], qb0, qb1) + sel_q(acc2[1], qb0, qb1);
    const float pg = sel_q(gacc[2], qb0, qb1) + sel_q(acc2[2], qb0, qb1);
    const float po = sel_q(gacc[3], qb0, qb1) + sel_q(acc2[3], qb0, qb1);
    const float h = lstm_cell(pi, pf, pg, po, cst);
    const f16 hf = (f16)h;
    hq[(t + 1) & 1][q][jcol] = hf;
    *hsp = hf;
    hsp += hstep;

    if (t + 1 < Tsz) {
      // xproj for t+1 from this slot (loaded 4 steps ago; cvt is VALU-only)
      f16x8 xa = pack_frag(a0, a1);
      f16x8 xb = pack_frag(b0, b1);
#pragma unroll
      for (int g = 0; g < 4; ++g) {
        floatx4 na;
        na[0] = bsum[g]; na[1] = bsum[g]; na[2] = bsum[g]; na[3] = bsum[g];
        na = MFMA(xa, wi[g][0], na);
        na = MFMA(xb, wi[g][1], na);
        gacc[g] = na;
      }
      // refill this slot with x(t+5)
      if (t + 5 < Tsz) {
        a0 = *(const float4*)xpn;        a1 = *(const float4*)(xpn + 4);
        b0 = *(const float4*)(xpn + 32); b1 = *(const float4*)(xpn + 36);
        xpn += xstep;
      }
    }
    lds_barrier();
  };

  for (int tb = 0; tb < Tsz; tb += 4) {
    step(tb + 0, rA0[0], rA1[0], rB0[0], rB1[0]);
    step(tb + 1, rA0[1], rA1[1], rB0[1], rB1[1]);
    step(tb + 2, rA0[2], rA1[2], rB0[2], rB1[2]);
    step(tb + 3, rA0[3], rA1[3], rB0[3], rB1[3]);
  }
}

// xg GEMM for layer-1 fwd. Output layout: xg[sb][t][w][l15][r*4+g] f16
// so each scan lane reads ONE coalesced f16x4. Grid 256.
__global__ __launch_bounds__(512, 1) void xg_gemm_l1(
    const f16* __restrict__ hs, const float* __restrict__ Wih,
    const float* __restrict__ bih, const float* __restrict__ bhh,
    f16* __restrict__ xg) {
  const int bg = (int)blockIdx.x & 15;
  const int tc = (int)blockIdx.x >> 4;
  const int bb = bg * 16;

  const int tid = threadIdx.x;
  const int lane = tid & 63;
  const int w = tid >> 6;
  const int l15 = lane & 15;
  const int q = lane >> 4;
  const int jcol = w * 16 + l15;

  f16x8 wi[4][8];
  float bsum[4];
#pragma unroll
  for (int g = 0; g < 4; ++g) {
    const int n = g * 128 + jcol;
#pragma unroll
    for (int kt = 0; kt < 8; ++kt) wi[g][kt] = load_wfrag(Wih, n, 256, kt * 32 + q * 8);
    bsum[g] = bih[n] + bhh[n];
  }

  const f16* ap = hs + ((size_t)(bb + l15) * Tsz + tc * 32) * 256 + q * 8;
  f16* op = xg + ((((size_t)(bg * 4 + q) * Tsz + tc * 32) * 8 + w) * 16 + l15) * 16;

  for (int tt = 0; tt < 32; ++tt) {
    f16x8 a[8];
#pragma unroll
    for (int kt = 0; kt < 8; ++kt) a[kt] = *(const f16x8*)(ap + kt * 32);
    ap += 256;

    floatx4 acc[4];
#pragma unroll
    for (int g = 0; g < 4; ++g) {
      acc[g][0] = bsum[g]; acc[g][1] = bsum[g];
      acc[g][2] = bsum[g]; acc[g][3] = bsum[g];
    }
#pragma unroll
    for (int kt = 0; kt < 8; ++kt)
#pragma unroll
      for (int g = 0; g < 4; ++g) acc[g] = MFMA(a[kt], wi[g][kt], acc[g]);

    f16x8 o0, o1;
#pragma unroll
    for (int e = 0; e < 8; ++e) {
      o0[e] = (f16)acc[e & 3][e >> 2];       // e = r*4+g
      o1[e] = (f16)acc[e & 3][2 + (e >> 2)];
    }
    *(f16x8*)op = o0;
    *(f16x8*)(op + 8) = o1;
    op += 2048;
  }
}

// Layer-1 forward scan from precomputed xg, with the L1-reverse single step
// (h0=c0=0 -> Whh vanishes) and FC head fused as a per-block epilogue.
// 64 blocks x 4 batches, 1 cell/lane, depth-4 copy-free ring.
__global__ __launch_bounds__(512, 1) void lstm_scan_l1x(
    const f16* __restrict__ xg, const float* __restrict__ Whh,
    const f16* __restrict__ hs, const float* __restrict__ Wr,
    const float* __restrict__ br1, const float* __restrict__ br2,
    const float* __restrict__ fc1w, const float* __restrict__ fc1b,
    const float* __restrict__ fc2w, const float* __restrict__ fc2b,
    float* __restrict__ out) {
  const int sb = (int)blockIdx.x;

  __shared__ __align__(16) f16 hq[2][4][144];
  __shared__ float hrow4[4][256];   // epilogue: hs[b][T-1][:]
  __shared__ float gact4[4][512];   // epilogue: reverse-step activations
  __shared__ float last4[4][256];   // epilogue: [h_fwd | h_rev]
  __shared__ float hid4[4][128];    // epilogue: relu(fc1 ...)

  const int tid = threadIdx.x;
  const int lane = tid & 63;
  const int w = tid >> 6;
  const int l15 = lane & 15;
  const int q = lane >> 4;
  const int jcol = w * 16 + l15;
  const int mrow = l15 & 3;
  const bool qb0 = (q & 1) != 0;
  const bool qb1 = (q & 2) != 0;

  f16x8 wh[4][4];
#pragma unroll
  for (int g = 0; g < 4; ++g) {
    const int n = g * 128 + jcol;
#pragma unroll
    for (int kt = 0; kt < 4; ++kt) wh[g][kt] = load_wfrag(Whh, n, Hsz, kt * 32 + q * 8);
  }

  for (int i = tid; i < 2 * 4 * 144; i += 512) (&hq[0][0][0])[i] = (f16)0.f;

  float cst = 0.f;

  const f16* gp = xg + (((size_t)sb * Tsz * 8 + w) * 16 + l15) * 16 + q * 4;
  f16x4 s0 = *(const f16x4*)gp;
  f16x4 s1 = *(const f16x4*)(gp + 2048);
  f16x4 s2 = *(const f16x4*)(gp + 4096);
  f16x4 s3 = *(const f16x4*)(gp + 6144);
  const f16* gpn = gp + 4 * 2048;

  __syncthreads();

  auto step = [&](int t, f16x4& sl) {
    f16x8 ah[4];
#pragma unroll
    for (int kt = 0; kt < 4; ++kt)
      ah[kt] = *(const f16x8*)(&hq[t & 1][mrow][kt * 32 + q * 8]);

    floatx4 gacc[4], acc2[4];
#pragma unroll
    for (int g = 0; g < 4; ++g) {
      const float v = (float)sl[g];
      gacc[g][0] = v; gacc[g][1] = v; gacc[g][2] = v; gacc[g][3] = v;
      floatx4 z; z[0] = 0.f; z[1] = 0.f; z[2] = 0.f; z[3] = 0.f;
      acc2[g] = MFMA(ah[2], wh[g][2], z);
      acc2[g] = MFMA(ah[3], wh[g][3], acc2[g]);
      gacc[g] = MFMA(ah[0], wh[g][0], gacc[g]);
      gacc[g] = MFMA(ah[1], wh[g][1], gacc[g]);
    }

    const float pi = sel_q(gacc[0], qb0, qb1) + sel_q(acc2[0], qb0, qb1);
    const float pf = sel_q(gacc[1], qb0, qb1) + sel_q(acc2[1], qb0, qb1);
    const float pg = sel_q(gacc[2], qb0, qb1) + sel_q(acc2[2], qb0, qb1);
    const float po = sel_q(gacc[3], qb0, qb1) + sel_q(acc2[3], qb0, qb1);
    const float h = lstm_cell(pi, pf, pg, po, cst);
    hq[(t + 1) & 1][q][jcol] = (f16)h;

    if (t + 4 < Tsz) {
      sl = *(const f16x4*)gpn;
      gpn += 2048;
    }
    lds_barrier();
  };

  for (int tb = 0; tb < Tsz; tb += 4) {
    step(tb + 0, s0);
    step(tb + 1, s1);
    step(tb + 2, s2);
    step(tb + 3, s3);
  }

  // ---------- epilogue: L1-reverse single step + FC head (4 batches) -------
  __syncthreads();
  {
    // hrow4 = hs[b][T-1][:] (fp32); last4[b][0:128] = h_fwd(T-1) from hq[0]
    const int b2 = tid >> 7, k2 = (tid & 127) * 2;
    const size_t row = (((size_t)(sb * 4 + b2) * Tsz) + (Tsz - 1)) * 256;
    hrow4[b2][k2] = (float)hs[row + k2];
    hrow4[b2][k2 + 1] = (float)hs[row + k2 + 1];
    last4[b2][tid & 127] = (float)hq[0][b2][tid & 127];
  }
  __syncthreads();
  {
    // reverse-step gates: thread = gate n, 4 batches share the Wr row
    const int n = tid;
    const float bias = br1[n] + br2[n];
    float a0 = bias, a1 = bias, a2 = bias, a3 = bias;
    const float* wr = Wr + (size_t)n * 256;
#pragma unroll 4
    for (int k = 0; k < 256; ++k) {
      const float wv = wr[k];
      a0 += wv * hrow4[0][k]; a1 += wv * hrow4[1][k];
      a2 += wv * hrow4[2][k]; a3 += wv * hrow4[3][k];
    }
    const bool tg = (n >= 256 && n < 384);
    gact4[0][n] = tg ? tanh_f(a0) : sigm_f(a0);
    gact4[1][n] = tg ? tanh_f(a1) : sigm_f(a1);
    gact4[2][n] = tg ? tanh_f(a2) : sigm_f(a2);
    gact4[3][n] = tg ? tanh_f(a3) : sigm_f(a3);
  }
  __syncthreads();
  {
    const int b = tid >> 7, j = tid & 127;
    const float c = gact4[b][j] * gact4[b][256 + j];   // sig(i)*tanh(g), c0=0
    last4[b][128 + j] = gact4[b][384 + j] * tanh_f(c);
  }
  __syncthreads();
  {
    const int b = tid >> 7, i = tid & 127;
    float a = fc1b[i];
    const float* w1 = fc1w + (size_t)i * 256;
#pragma unroll 4
    for (int k = 0; k < 256; ++k) a += last4[b][k] * w1[k];
    hid4[b][i] = fmaxf(a, 0.f);
  }
  __syncthreads();
  if (tid < 4) {
    float s = fc2b[0];
    for (int k = 0; k < 128; ++k) s += hid4[tid][k] * fc2w[k];
    out[sb * 4 + tid] = s;
  }
}

// Fallback layer-1 scan (reads hs directly) for small ws. 16 blocks.
__global__ __launch_bounds__(512, 1) void lstm_scan_l1_fb(
    const f16* __restrict__ hs,
    const float* __restrict__ Wih, const float* __restrict__ Whh,
    const float* __restrict__ bih, const float* __restrict__ bhh,
    float* __restrict__ hfinal) {
  const int bb = (int)blockIdx.x * 16;
  __shared__ __align__(16) f16 hq[2][16][136];
  __shared__ __align__(16) f16 xq[2][16][264];

  const int tid = threadIdx.x;
  const int lane = tid & 63;
  const int w = tid >> 6;
  const int l15 = lane & 15;
  const int q = lane >> 4;
  const int jcol = w * 16 + l15;

  f16x8 wi[4][8], wh[4][4];
  float bsum[4];
#pragma unroll
  for (int g = 0; g < 4; ++g) {
    const int n = g * 128 + jcol;
#pragma unroll
    for (int kt = 0; kt < 8; ++kt) wi[g][kt] = load_wfrag(Wih, n, 256, kt * 32 + q * 8);
#pragma unroll
    for (int kt = 0; kt < 4; ++kt) wh[g][kt] = load_wfrag(Whh, n, Hsz, kt * 32 + q * 8);
    bsum[g] = bih[n] + bhh[n];
  }
  for (int i = tid; i < 2 * 16 * 136; i += 512) (&hq[0][0][0])[i] = (f16)0.f;
  float cst[4] = {0.f, 0.f, 0.f, 0.f};

  floatx4 gacc[4];
  {
    const f16* pp = hs + (size_t)(bb + l15) * Tsz * 256 + q * 8;
#pragma unroll
    for (int g = 0; g < 4; ++g) {
      gacc[g][0] = bsum[g]; gacc[g][1] = bsum[g];
      gacc[g][2] = bsum[g]; gacc[g][3] = bsum[g];
    }
#pragma unroll
    for (int kt = 0; kt < 8; ++kt) {
      f16x8 xa = *(const f16x8*)(pp + kt * 32);
#pragma unroll
      for (int g = 0; g < 4; ++g) gacc[g] = MFMA(xa, wi[g][kt], gacc[g]);
    }
  }
  const int sm = tid >> 5;
  const int sc = tid & 31;
  const f16* spg = hs + (size_t)(bb + sm) * Tsz * 256 + sc * 8;
  const f16* spn = spg + 3 * 256;
  f16x8 ld;
  *(f16x8*)(&xq[1][sm][sc * 8]) = *(const f16x8*)(spg + 256);
  ld = *(const f16x8*)(spg + 2 * 256);
  __syncthreads();

  for (int t = 0; t < Tsz; ++t) {
    f16x8 xa[8];
    if (t + 1 < Tsz) {
      const f16* xrow = &xq[(t + 1) & 1][l15][0];
#pragma unroll
      for (int kt = 0; kt < 8; ++kt) xa[kt] = *(const f16x8*)(xrow + kt * 32 + q * 8);
    }
    f16x8 ah[4];
#pragma unroll
    for (int kt = 0; kt < 4; ++kt)
      ah[kt] = *(const f16x8*)(&hq[t & 1][l15][kt * 32 + q * 8]);
#pragma unroll
    for (int kt = 0; kt < 4; ++kt)
#pragma unroll
      for (int g = 0; g < 4; ++g) gacc[g] = MFMA(ah[kt], wh[g][kt], gacc[g]);

#pragma unroll
    for (int r = 0; r < 4; ++r) {
      const float h = lstm_cell(gacc[0][r], gacc[1][r], gacc[2][r], gacc[3][r], cst[r]);
      hq[(t + 1) & 1][4 * q + r][jcol] = (f16)h;
      if (t == Tsz - 1) hfinal[(size_t)(bb + 4 * q + r) * Hsz + jcol] = h;
    }
    if (t + 2 < Tsz) *(f16x8*)(&xq[t & 1][sm][sc * 8]) = ld;
    if (t + 3 < Tsz) { ld = *(const f16x8*)spn; spn += 256; }
    if (t + 1 < Tsz) {
      floatx4 nacc[4];
#pragma unroll
      for (int g = 0; g < 4; ++g) {
        nacc[g][0] = bsum[g]; nacc[g][1] = bsum[g];
        nacc[g][2] = bsum[g]; nacc[g][3] = bsum[g];
      }
#pragma unroll
      for (int kt = 0; kt < 8; ++kt)
#pragma unroll
        for (int g = 0; g < 4; ++g) nacc[g] = MFMA(xa[kt], wi[g][kt], nacc[g]);
#pragma unroll
      for (int g = 0; g < 4; ++g) gacc[g] = nacc[g];
    }
    lds_barrier();
  }
}

// Fallback tail. 1 block/batch.
__global__ __launch_bounds__(512) void tail_kernel(
    const f16* __restrict__ hs, const float* __restrict__ hfinal,
    const float* __restrict__ Wr, const float* __restrict__ br1,
    const float* __restrict__ br2, const float* __restrict__ fc1w,
    const float* __restrict__ fc1b, const float* __restrict__ fc2w,
    const float* __restrict__ fc2b, float* __restrict__ out) {
  const int b = blockIdx.x;
  const int tid = threadIdx.x;
  __shared__ float hrow[256];
  __shared__ float gact[512];
  __shared__ float last[256];
  __shared__ float hid[128];
  __shared__ float psum[128];

  const size_t row = ((size_t)b * Tsz + (Tsz - 1)) * 256;
  if (tid < 256) hrow[tid] = (float)hs[row + tid];
  __syncthreads();

  {
    float a = br1[tid] + br2[tid];
    const float* wr = Wr + (size_t)tid * 256;
#pragma unroll 8
    for (int k = 0; k < 256; ++k) a += hrow[k] * wr[k];
    gact[tid] = (tid >= 256 && tid < 384) ? tanh_f(a) : sigm_f(a);
  }
  __syncthreads();

  if (tid < 128) {
    const float c = gact[tid] * gact[256 + tid];
    const float hb = gact[384 + tid] * tanh_f(c);
    last[tid] = hfinal[(size_t)b * Hsz + tid];
    last[128 + tid] = hb;
  }
  __syncthreads();

  if (tid < 128) {
    float a = fc1b[tid];
    const float* w1 = fc1w + (size_t)tid * 256;
#pragma unroll 8
    for (int k = 0; k < 256; ++k) a += last[k] * w1[k];
    hid[tid] = fmaxf(a, 0.f);
  }
  __syncthreads();
  if (tid < 128) psum[tid] = hid[tid] * fc2w[tid];
  __syncthreads();
  if (tid == 0) {
    float s = fc2b[0];
    for (int k = 0; k < 128; ++k) s += psum[k];
    out[b] = s;
  }
}

extern "C" void kernel_launch(void* const* d_in, const int* in_sizes, int n_in,
                              void* d_out, int out_size, void* d_ws, size_t ws_size,
                              hipStream_t stream) {
  (void)in_sizes; (void)n_in; (void)out_size;
  const float* x = (const float*)d_in[0];
  const float* Wih_l0 = (const float*)d_in[1];
  const float* Whh_l0 = (const float*)d_in[2];
  const float* bih_l0 = (const float*)d_in[3];
  const float* bhh_l0 = (const float*)d_in[4];
  const float* Wih_l0r = (const float*)d_in[5];
  const float* Whh_l0r = (const float*)d_in[6];
  const float* bih_l0r = (const float*)d_in[7];
  const float* bhh_l0r = (const float*)d_in[8];
  const float* Wih_l1 = (const float*)d_in[9];
  const float* Whh_l1 = (const float*)d_in[10];
  const float* bih_l1 = (const float*)d_in[11];
  const float* bhh_l1 = (const float*)d_in[12];
  const float* Wih_l1r = (const float*)d_in[13];
  // d_in[14] = W_hh_l1r unused (reverse h0 = 0)
  const float* bih_l1r = (const float*)d_in[15];
  const float* bhh_l1r = (const float*)d_in[16];
  const float* fc1w = (const float*)d_in[17];
  const float* fc1b = (const float*)d_in[18];
  const float* fc2w = (const float*)d_in[19];
  const float* fc2b = (const float*)d_in[20];
  float* out = (float*)d_out;

  char* ws = (char*)d_ws;
  const size_t M = (size_t)Bsz * Tsz;        // 131072
  const size_t HSB = M * 256 * 2;            // 67.1 MB  hs in f16
  const size_t HFB = (size_t)Bsz * Hsz * 4;  // 131 KB   fallback hfinal
  const size_t XGB = (size_t)64 * Tsz * 8 * 16 * 16 * 2;  // 134 MB l1 xg f16
  const size_t need_min = HSB + HFB;
  const size_t need_full = need_min + XGB;
  if (ws_size < need_min) return;
  const bool fast = ws_size >= need_full;

  size_t off = 0;
  f16* hsb = (f16*)(ws + off); off += HSB;
  float* hfinal = (float*)(ws + off); off += HFB;
  f16* xgb = fast ? (f16*)(ws + off) : nullptr;

  lstm_scan_l0<<<dim3(128), dim3(512), 0, stream>>>(
      x, Wih_l0, Whh_l0, bih_l0, bhh_l0, Wih_l0r, Whh_l0r, bih_l0r, bhh_l0r, hsb);

  if (fast) {
    xg_gemm_l1<<<dim3(256), dim3(512), 0, stream>>>(hsb, Wih_l1, bih_l1, bhh_l1, xgb);
    lstm_scan_l1x<<<dim3(64), dim3(512), 0, stream>>>(
        xgb, Whh_l1, hsb, Wih_l1r, bih_l1r, bhh_l1r, fc1w, fc1b, fc2w, fc2b, out);
  } else {
    lstm_scan_l1_fb<<<dim3(16), dim3(512), 0, stream>>>(
        hsb, Wih_l1, Whh_l1, bih_l1, bhh_l1, hfinal);
    tail_kernel<<<dim3(256), dim3(512), 0, stream>>>(
        hsb, hfinal, Wih_l1r, bih_l1r, bhh_l1r, fc1w, fc1b, fc2w, fc2b, out);
  }
}

// Round 11
// 776.725 us; speedup vs baseline: 1.2512x; 1.2512x over previous
//
#include <hip/hip_runtime.h>

#define Bsz 256
#define Tsz 512
#define Isz 64
#define Hsz 128
#define G4  512   // 4*H

typedef _Float16 f16;
typedef _Float16 f16x8 __attribute__((ext_vector_type(8)));
typedef _Float16 f16x4 __attribute__((ext_vector_type(4)));
typedef float floatx4 __attribute__((ext_vector_type(4)));

#define MFMA(A, B, C) __builtin_amdgcn_mfma_f32_16x16x32_f16((A), (B), (C), 0, 0, 0)

// LDS-only barrier: drains lgkmcnt but NOT vmcnt -> in-loop global traffic
// (prefetch loads, hs stores) never serializes a step.
__device__ __forceinline__ void lds_barrier() {
  asm volatile("s_waitcnt lgkmcnt(0)\n\ts_barrier" ::: "memory");
}

__device__ __forceinline__ float sigm_f(float x) {
  float e = __builtin_amdgcn_exp2f(x * -1.4426950408889634f);
  return __builtin_amdgcn_rcpf(1.0f + e);
}
__device__ __forceinline__ float tanh_f(float x) {
  float e = __builtin_amdgcn_exp2f(x * -2.8853900817779268f);
  return 2.0f * __builtin_amdgcn_rcpf(1.0f + e) - 1.0f;
}

// fp32 -> fp16 convert, 4 elems/thread
__global__ void cvt_f32_f16(const float* __restrict__ in, f16* __restrict__ out, int n4) {
  int i = blockIdx.x * blockDim.x + threadIdx.x;
  if (i < n4) {
    float4 v = ((const float4*)in)[i];
    f16x4 o;
    o[0] = (f16)v.x; o[1] = (f16)v.y; o[2] = (f16)v.z; o[3] = (f16)v.w;
    ((f16x4*)out)[i] = o;
  }
}

__device__ __forceinline__ f16x8 load_wfrag(const float* __restrict__ W, int n, int stride, int k) {
  const float* p = W + (size_t)n * stride + k;
  float4 a = *(const float4*)p;
  float4 b = *(const float4*)(p + 4);
  f16x8 r;
  r[0] = (f16)a.x; r[1] = (f16)a.y; r[2] = (f16)a.z; r[3] = (f16)a.w;
  r[4] = (f16)b.x; r[5] = (f16)b.y; r[6] = (f16)b.z; r[7] = (f16)b.w;
  return r;
}

// Shared-denominator LSTM cell: 5 exp2 + 2 rcp.
__device__ __forceinline__ float lstm_cell(float ipre, float fpre, float gpre,
                                           float opre, float& c) {
  const float ei = __builtin_amdgcn_exp2f(fminf(ipre * -1.4426950408889634f, 30.f));
  const float ef = __builtin_amdgcn_exp2f(fminf(fpre * -1.4426950408889634f, 30.f));
  const float eg = __builtin_amdgcn_exp2f(fminf(gpre * -2.8853900817779268f, 30.f));
  const float eo = __builtin_amdgcn_exp2f(fminf(opre * -1.4426950408889634f, 30.f));
  const float pf1 = 1.f + ef;
  const float P = (1.f + ei) * (1.f + eg);
  const float num = fmaf(c, P, pf1 * (1.f - eg));
  const float cn = num * __builtin_amdgcn_rcpf(pf1 * P);
  c = cn;
  const float ec = __builtin_amdgcn_exp2f(fminf(cn * -2.8853900817779268f, 30.f));
  return (1.f - ec) * __builtin_amdgcn_rcpf((1.f + eo) * (1.f + ec));
}

// Extract acc[r=q] (row 4q+q == lane's batch) with 3 cndmask.
__device__ __forceinline__ float sel_q(const floatx4& a, bool qb0, bool qb1) {
  const float a01 = qb0 ? a[1] : a[0];
  const float a23 = qb0 ? a[3] : a[2];
  return qb1 ? a23 : a01;
}

// Layer-0 BiLSTM scan, 4 batches/block, 1 cell/lane. 128 blocks (0..63 fwd,
// 64..127 rev) x 512 thr. Depth-4 f16 x-prefetch ring, NO register copies
// (t-loop unrolled x4, each body owns a fixed slot). hq stride 144 (2-way max
// LDS aliasing = free). PROVEN round-8 form: 297 us, 1390 cyc/step.
__global__ __launch_bounds__(512, 1) void lstm_scan_l0(
    const f16* __restrict__ xf,
    const float* __restrict__ Wih_f, const float* __restrict__ Whh_f,
    const float* __restrict__ bih_f, const float* __restrict__ bhh_f,
    const float* __restrict__ Wih_r, const float* __restrict__ Whh_r,
    const float* __restrict__ bih_r, const float* __restrict__ bhh_r,
    f16* __restrict__ hs) {
  const int dir = ((int)blockIdx.x >= 64) ? 1 : 0;
  const int bb = ((int)blockIdx.x & 63) * 4;
  const float* __restrict__ Wih = dir ? Wih_r : Wih_f;
  const float* __restrict__ Whh = dir ? Whh_r : Whh_f;
  const float* __restrict__ bih = dir ? bih_r : bih_f;
  const float* __restrict__ bhh = dir ? bhh_r : bhh_f;

  __shared__ __align__(16) f16 hq[2][4][144];

  const int tid = threadIdx.x;
  const int lane = tid & 63;
  const int w = tid >> 6;
  const int l15 = lane & 15;
  const int q = lane >> 4;
  const int jcol = w * 16 + l15;
  const int mrow = l15 & 3;
  const bool qb0 = (q & 1) != 0;
  const bool qb1 = (q & 2) != 0;

  f16x8 wi[4][2], wh[4][4];
  float bsum[4];
#pragma unroll
  for (int g = 0; g < 4; ++g) {
    const int n = g * 128 + jcol;
#pragma unroll
    for (int kt = 0; kt < 2; ++kt) wi[g][kt] = load_wfrag(Wih, n, Isz, kt * 32 + q * 8);
#pragma unroll
    for (int kt = 0; kt < 4; ++kt) wh[g][kt] = load_wfrag(Whh, n, Hsz, kt * 32 + q * 8);
    bsum[g] = bih[n] + bhh[n];
  }

  for (int i = tid; i < 2 * 4 * 144; i += 512) (&hq[0][0][0])[i] = (f16)0.f;

  float cst = 0.f;
  const int t0 = dir ? (Tsz - 1) : 0;
  const int dt = dir ? -1 : 1;
  const ptrdiff_t xstep = (ptrdiff_t)dt * Isz;

  const f16* xp = xf + ((size_t)(bb + mrow) * Tsz + t0) * Isz + q * 8;

  // prime gacc = bias + xproj(t0)
  floatx4 gacc[4];
  {
    f16x8 x0 = *(const f16x8*)xp;
    f16x8 x1 = *(const f16x8*)(xp + 32);
#pragma unroll
    for (int g = 0; g < 4; ++g) {
      gacc[g][0] = bsum[g]; gacc[g][1] = bsum[g];
      gacc[g][2] = bsum[g]; gacc[g][3] = bsum[g];
      gacc[g] = MFMA(x0, wi[g][0], gacc[g]);
      gacc[g] = MFMA(x1, wi[g][1], gacc[g]);
    }
  }

  // ring slot s holds x(t+1) for steps t == s (mod 4); primed with x(1..4)
  f16x8 r0a = *(const f16x8*)(xp + 1 * xstep), r0b = *(const f16x8*)(xp + 1 * xstep + 32);
  f16x8 r1a = *(const f16x8*)(xp + 2 * xstep), r1b = *(const f16x8*)(xp + 2 * xstep + 32);
  f16x8 r2a = *(const f16x8*)(xp + 3 * xstep), r2b = *(const f16x8*)(xp + 3 * xstep + 32);
  f16x8 r3a = *(const f16x8*)(xp + 4 * xstep), r3b = *(const f16x8*)(xp + 4 * xstep + 32);
  const f16* xpn = xp + 5 * xstep;   // next address to load: x(t+5) at step t

  f16* hsp = hs + ((size_t)(bb + q) * Tsz + t0) * 256 + dir * 128 + jcol;
  const ptrdiff_t hstep = (ptrdiff_t)dt * 256;

  __syncthreads();

  auto step = [&](int t, f16x8& ra, f16x8& rb) {
    f16x8 ah[4];
#pragma unroll
    for (int kt = 0; kt < 4; ++kt)
      ah[kt] = *(const f16x8*)(&hq[t & 1][mrow][kt * 32 + q * 8]);
#pragma unroll
    for (int kt = 0; kt < 4; ++kt)
#pragma unroll
      for (int g = 0; g < 4; ++g) gacc[g] = MFMA(ah[kt], wh[g][kt], gacc[g]);

    const float h = lstm_cell(sel_q(gacc[0], qb0, qb1), sel_q(gacc[1], qb0, qb1),
                              sel_q(gacc[2], qb0, qb1), sel_q(gacc[3], qb0, qb1), cst);
    const f16 hf = (f16)h;
    hq[(t + 1) & 1][q][jcol] = hf;
    *hsp = hf;
    hsp += hstep;

    if (t + 1 < Tsz) {
      // xproj for t+1 from this body's ring slot (loaded 4 steps ago)
#pragma unroll
      for (int g = 0; g < 4; ++g) {
        floatx4 na;
        na[0] = bsum[g]; na[1] = bsum[g]; na[2] = bsum[g]; na[3] = bsum[g];
        na = MFMA(ra, wi[g][0], na);
        na = MFMA(rb, wi[g][1], na);
        gacc[g] = na;
      }
      // refill this slot with x(t+5), consumed at step t+4
      if (t + 5 < Tsz) {
        ra = *(const f16x8*)xpn;
        rb = *(const f16x8*)(xpn + 32);
        xpn += xstep;
      }
    }
    lds_barrier();
  };

  for (int tb = 0; tb < Tsz; tb += 4) {
    step(tb + 0, r0a, r0b);
    step(tb + 1, r1a, r1b);
    step(tb + 2, r2a, r2b);
    step(tb + 3, r3a, r3b);
  }
}

// xg GEMM for layer-1 fwd. Output layout: xg[sb][t][w][l15][r*4+g] f16 so
// each scan lane reads ONE coalesced f16x4. Grid 256. A-loads double-buffered
// (load->use distance = 1 iter) so per-iter load latency is hidden.
__global__ __launch_bounds__(512, 1) void xg_gemm_l1(
    const f16* __restrict__ hs, const float* __restrict__ Wih,
    const float* __restrict__ bih, const float* __restrict__ bhh,
    f16* __restrict__ xg) {
  const int bg = (int)blockIdx.x & 15;
  const int tc = (int)blockIdx.x >> 4;
  const int bb = bg * 16;

  const int tid = threadIdx.x;
  const int lane = tid & 63;
  const int w = tid >> 6;
  const int l15 = lane & 15;
  const int q = lane >> 4;
  const int jcol = w * 16 + l15;

  f16x8 wi[4][8];
  float bsum[4];
#pragma unroll
  for (int g = 0; g < 4; ++g) {
    const int n = g * 128 + jcol;
#pragma unroll
    for (int kt = 0; kt < 8; ++kt) wi[g][kt] = load_wfrag(Wih, n, 256, kt * 32 + q * 8);
    bsum[g] = bih[n] + bhh[n];
  }

  const f16* ap = hs + ((size_t)(bb + l15) * Tsz + tc * 32) * 256 + q * 8;
  f16* op = xg + ((((size_t)(bg * 4 + q) * Tsz + tc * 32) * 8 + w) * 16 + l15) * 16;

  auto compute_store = [&](f16x8 (&a)[8]) {
    floatx4 acc[4];
#pragma unroll
    for (int g = 0; g < 4; ++g) {
      acc[g][0] = bsum[g]; acc[g][1] = bsum[g];
      acc[g][2] = bsum[g]; acc[g][3] = bsum[g];
    }
#pragma unroll
    for (int kt = 0; kt < 8; ++kt)
#pragma unroll
      for (int g = 0; g < 4; ++g) acc[g] = MFMA(a[kt], wi[g][kt], acc[g]);

    f16x8 o0, o1;
#pragma unroll
    for (int e = 0; e < 8; ++e) {
      o0[e] = (f16)acc[e & 3][e >> 2];       // e = r*4+g
      o1[e] = (f16)acc[e & 3][2 + (e >> 2)];
    }
    *(f16x8*)op = o0;
    *(f16x8*)(op + 8) = o1;
    op += 2048;
  };

  f16x8 a0[8], a1[8];
#pragma unroll
  for (int kt = 0; kt < 8; ++kt) a0[kt] = *(const f16x8*)(ap + kt * 32);
  ap += 256;

  for (int tt = 0; tt < 32; tt += 2) {
    // prefetch tt+1 while computing tt
#pragma unroll
    for (int kt = 0; kt < 8; ++kt) a1[kt] = *(const f16x8*)(ap + kt * 32);
    ap += 256;
    compute_store(a0);
    // prefetch tt+2 while computing tt+1
    if (tt + 2 < 32) {
#pragma unroll
      for (int kt = 0; kt < 8; ++kt) a0[kt] = *(const f16x8*)(ap + kt * 32);
      ap += 256;
    }
    compute_store(a1);
  }
}

// Layer-1 forward scan from precomputed xg (round-8 proven step body), with
// the L1-reverse single step (h0=c0=0 -> Whh vanishes) + FC head fused as a
// per-block epilogue. 64 blocks x 4 batches, 1 cell/lane, depth-4 ring.
__global__ __launch_bounds__(512, 1) void lstm_scan_l1x(
    const f16* __restrict__ xg, const float* __restrict__ Whh,
    const f16* __restrict__ hs, const float* __restrict__ Wr,
    const float* __restrict__ br1, const float* __restrict__ br2,
    const float* __restrict__ fc1w, const float* __restrict__ fc1b,
    const float* __restrict__ fc2w, const float* __restrict__ fc2b,
    float* __restrict__ out) {
  const int sb = (int)blockIdx.x;

  __shared__ __align__(16) f16 hq[2][4][144];
  __shared__ float hrow4[4][256];   // epilogue: hs[b][T-1][:]
  __shared__ float gact4[4][512];   // epilogue: reverse-step activations
  __shared__ float last4[4][256];   // epilogue: [h_fwd | h_rev]
  __shared__ float hid4[4][128];    // epilogue: relu(fc1 ...)

  const int tid = threadIdx.x;
  const int lane = tid & 63;
  const int w = tid >> 6;
  const int l15 = lane & 15;
  const int q = lane >> 4;
  const int jcol = w * 16 + l15;
  const int mrow = l15 & 3;
  const bool qb0 = (q & 1) != 0;
  const bool qb1 = (q & 2) != 0;

  f16x8 wh[4][4];
#pragma unroll
  for (int g = 0; g < 4; ++g) {
    const int n = g * 128 + jcol;
#pragma unroll
    for (int kt = 0; kt < 4; ++kt) wh[g][kt] = load_wfrag(Whh, n, Hsz, kt * 32 + q * 8);
  }

  for (int i = tid; i < 2 * 4 * 144; i += 512) (&hq[0][0][0])[i] = (f16)0.f;

  float cst = 0.f;

  const f16* gp = xg + (((size_t)sb * Tsz * 8 + w) * 16 + l15) * 16 + q * 4;
  // ring slot s = xg(t) for t == s (mod 4); primed with xg(0..3)
  f16x4 s0 = *(const f16x4*)gp;
  f16x4 s1 = *(const f16x4*)(gp + 2048);
  f16x4 s2 = *(const f16x4*)(gp + 4096);
  f16x4 s3 = *(const f16x4*)(gp + 6144);
  const f16* gpn = gp + 4 * 2048;   // next load: xg(t+4) at step t

  __syncthreads();

  auto step = [&](int t, f16x4& sl) {
    f16x8 ah[4];
#pragma unroll
    for (int kt = 0; kt < 4; ++kt)
      ah[kt] = *(const f16x8*)(&hq[t & 1][mrow][kt * 32 + q * 8]);

    floatx4 gacc[4];
#pragma unroll
    for (int g = 0; g < 4; ++g) {
      const float v = (float)sl[g];            // broadcast: only r=q consumed
      gacc[g][0] = v; gacc[g][1] = v; gacc[g][2] = v; gacc[g][3] = v;
    }
#pragma unroll
    for (int kt = 0; kt < 4; ++kt)
#pragma unroll
      for (int g = 0; g < 4; ++g) gacc[g] = MFMA(ah[kt], wh[g][kt], gacc[g]);

    const float h = lstm_cell(sel_q(gacc[0], qb0, qb1), sel_q(gacc[1], qb0, qb1),
                              sel_q(gacc[2], qb0, qb1), sel_q(gacc[3], qb0, qb1), cst);
    hq[(t + 1) & 1][q][jcol] = (f16)h;

    // refill this slot with xg(t+4)
    if (t + 4 < Tsz) {
      sl = *(const f16x4*)gpn;
      gpn += 2048;
    }
    lds_barrier();
  };

  for (int tb = 0; tb < Tsz; tb += 4) {
    step(tb + 0, s0);
    step(tb + 1, s1);
    step(tb + 2, s2);
    step(tb + 3, s3);
  }

  // ---------- epilogue: L1-reverse single step + FC head (4 batches) -------
  __syncthreads();
  {
    // hrow4 = hs[b][T-1][:] (fp32); last4[b][0:128] = h_fwd(T-1) from hq[0]
    const int b2 = tid >> 7, k2 = (tid & 127) * 2;
    const size_t row = (((size_t)(sb * 4 + b2) * Tsz) + (Tsz - 1)) * 256;
    hrow4[b2][k2] = (float)hs[row + k2];
    hrow4[b2][k2 + 1] = (float)hs[row + k2 + 1];
    last4[b2][tid & 127] = (float)hq[0][b2][tid & 127];
  }
  __syncthreads();
  {
    // reverse-step gates: thread = gate n, 4 batches share the Wr row
    const int n = tid;
    const float bias = br1[n] + br2[n];
    float a0 = bias, a1 = bias, a2 = bias, a3 = bias;
    const float* wr = Wr + (size_t)n * 256;
#pragma unroll 4
    for (int k = 0; k < 256; ++k) {
      const float wv = wr[k];
      a0 += wv * hrow4[0][k]; a1 += wv * hrow4[1][k];
      a2 += wv * hrow4[2][k]; a3 += wv * hrow4[3][k];
    }
    const bool tg = (n >= 256 && n < 384);
    gact4[0][n] = tg ? tanh_f(a0) : sigm_f(a0);
    gact4[1][n] = tg ? tanh_f(a1) : sigm_f(a1);
    gact4[2][n] = tg ? tanh_f(a2) : sigm_f(a2);
    gact4[3][n] = tg ? tanh_f(a3) : sigm_f(a3);
  }
  __syncthreads();
  {
    const int b = tid >> 7, j = tid & 127;
    const float c = gact4[b][j] * gact4[b][256 + j];   // sig(i)*tanh(g), c0=0
    last4[b][128 + j] = gact4[b][384 + j] * tanh_f(c);
  }
  __syncthreads();
  {
    const int b = tid >> 7, i = tid & 127;
    float a = fc1b[i];
    const float* w1 = fc1w + (size_t)i * 256;
#pragma unroll 4
    for (int k = 0; k < 256; ++k) a += last4[b][k] * w1[k];
    hid4[b][i] = fmaxf(a, 0.f);
  }
  __syncthreads();
  if (tid < 4) {
    float s = fc2b[0];
    for (int k = 0; k < 128; ++k) s += hid4[tid][k] * fc2w[k];
    out[sb * 4 + tid] = s;
  }
}

// Fallback layer-1 scan (reads hs directly) for small ws. 16 blocks.
__global__ __launch_bounds__(512, 1) void lstm_scan_l1_fb(
    const f16* __restrict__ hs,
    const float* __restrict__ Wih, const float* __restrict__ Whh,
    const float* __restrict__ bih, const float* __restrict__ bhh,
    float* __restrict__ hfinal) {
  const int bb = (int)blockIdx.x * 16;
  __shared__ __align__(16) f16 hq[2][16][136];
  __shared__ __align__(16) f16 xq[2][16][264];

  const int tid = threadIdx.x;
  const int lane = tid & 63;
  const int w = tid >> 6;
  const int l15 = lane & 15;
  const int q = lane >> 4;
  const int jcol = w * 16 + l15;

  f16x8 wi[4][8], wh[4][4];
  float bsum[4];
#pragma unroll
  for (int g = 0; g < 4; ++g) {
    const int n = g * 128 + jcol;
#pragma unroll
    for (int kt = 0; kt < 8; ++kt) wi[g][kt] = load_wfrag(Wih, n, 256, kt * 32 + q * 8);
#pragma unroll
    for (int kt = 0; kt < 4; ++kt) wh[g][kt] = load_wfrag(Whh, n, Hsz, kt * 32 + q * 8);
    bsum[g] = bih[n] + bhh[n];
  }
  for (int i = tid; i < 2 * 16 * 136; i += 512) (&hq[0][0][0])[i] = (f16)0.f;
  float cst[4] = {0.f, 0.f, 0.f, 0.f};

  floatx4 gacc[4];
  {
    const f16* pp = hs + (size_t)(bb + l15) * Tsz * 256 + q * 8;
#pragma unroll
    for (int g = 0; g < 4; ++g) {
      gacc[g][0] = bsum[g]; gacc[g][1] = bsum[g];
      gacc[g][2] = bsum[g]; gacc[g][3] = bsum[g];
    }
#pragma unroll
    for (int kt = 0; kt < 8; ++kt) {
      f16x8 xa = *(const f16x8*)(pp + kt * 32);
#pragma unroll
      for (int g = 0; g < 4; ++g) gacc[g] = MFMA(xa, wi[g][kt], gacc[g]);
    }
  }
  const int sm = tid >> 5;
  const int sc = tid & 31;
  const f16* spg = hs + (size_t)(bb + sm) * Tsz * 256 + sc * 8;
  const f16* spn = spg + 3 * 256;
  f16x8 ld;
  *(f16x8*)(&xq[1][sm][sc * 8]) = *(const f16x8*)(spg + 256);
  ld = *(const f16x8*)(spg + 2 * 256);
  __syncthreads();

  for (int t = 0; t < Tsz; ++t) {
    f16x8 xa[8];
    if (t + 1 < Tsz) {
      const f16* xrow = &xq[(t + 1) & 1][l15][0];
#pragma unroll
      for (int kt = 0; kt < 8; ++kt) xa[kt] = *(const f16x8*)(xrow + kt * 32 + q * 8);
    }
    f16x8 ah[4];
#pragma unroll
    for (int kt = 0; kt < 4; ++kt)
      ah[kt] = *(const f16x8*)(&hq[t & 1][l15][kt * 32 + q * 8]);
#pragma unroll
    for (int kt = 0; kt < 4; ++kt)
#pragma unroll
      for (int g = 0; g < 4; ++g) gacc[g] = MFMA(ah[kt], wh[g][kt], gacc[g]);

#pragma unroll
    for (int r = 0; r < 4; ++r) {
      const float h = lstm_cell(gacc[0][r], gacc[1][r], gacc[2][r], gacc[3][r], cst[r]);
      hq[(t + 1) & 1][4 * q + r][jcol] = (f16)h;
      if (t == Tsz - 1) hfinal[(size_t)(bb + 4 * q + r) * Hsz + jcol] = h;
    }
    if (t + 2 < Tsz) *(f16x8*)(&xq[t & 1][sm][sc * 8]) = ld;
    if (t + 3 < Tsz) { ld = *(const f16x8*)spn; spn += 256; }
    if (t + 1 < Tsz) {
      floatx4 nacc[4];
#pragma unroll
      for (int g = 0; g < 4; ++g) {
        nacc[g][0] = bsum[g]; nacc[g][1] = bsum[g];
        nacc[g][2] = bsum[g]; nacc[g][3] = bsum[g];
      }
#pragma unroll
      for (int kt = 0; kt < 8; ++kt)
#pragma unroll
        for (int g = 0; g < 4; ++g) nacc[g] = MFMA(xa[kt], wi[g][kt], nacc[g]);
#pragma unroll
      for (int g = 0; g < 4; ++g) gacc[g] = nacc[g];
    }
    lds_barrier();
  }
}

// Fallback tail. 1 block/batch.
__global__ __launch_bounds__(512) void tail_kernel(
    const f16* __restrict__ hs, const float* __restrict__ hfinal,
    const float* __restrict__ Wr, const float* __restrict__ br1,
    const float* __restrict__ br2, const float* __restrict__ fc1w,
    const float* __restrict__ fc1b, const float* __restrict__ fc2w,
    const float* __restrict__ fc2b, float* __restrict__ out) {
  const int b = blockIdx.x;
  const int tid = threadIdx.x;
  __shared__ float hrow[256];
  __shared__ float gact[512];
  __shared__ float last[256];
  __shared__ float hid[128];
  __shared__ float psum[128];

  const size_t row = ((size_t)b * Tsz + (Tsz - 1)) * 256;
  if (tid < 256) hrow[tid] = (float)hs[row + tid];
  __syncthreads();

  {
    float a = br1[tid] + br2[tid];
    const float* wr = Wr + (size_t)tid * 256;
#pragma unroll 8
    for (int k = 0; k < 256; ++k) a += hrow[k] * wr[k];
    gact[tid] = (tid >= 256 && tid < 384) ? tanh_f(a) : sigm_f(a);
  }
  __syncthreads();

  if (tid < 128) {
    const float c = gact[tid] * gact[256 + tid];
    const float hb = gact[384 + tid] * tanh_f(c);
    last[tid] = hfinal[(size_t)b * Hsz + tid];
    last[128 + tid] = hb;
  }
  __syncthreads();

  if (tid < 128) {
    float a = fc1b[tid];
    const float* w1 = fc1w + (size_t)tid * 256;
#pragma unroll 8
    for (int k = 0; k < 256; ++k) a += last[k] * w1[k];
    hid[tid] = fmaxf(a, 0.f);
  }
  __syncthreads();
  if (tid < 128) psum[tid] = hid[tid] * fc2w[tid];
  __syncthreads();
  if (tid == 0) {
    float s = fc2b[0];
    for (int k = 0; k < 128; ++k) s += psum[k];
    out[b] = s;
  }
}

extern "C" void kernel_launch(void* const* d_in, const int* in_sizes, int n_in,
                              void* d_out, int out_size, void* d_ws, size_t ws_size,
                              hipStream_t stream) {
  (void)in_sizes; (void)n_in; (void)out_size;
  const float* x = (const float*)d_in[0];
  const float* Wih_l0 = (const float*)d_in[1];
  const float* Whh_l0 = (const float*)d_in[2];
  const float* bih_l0 = (const float*)d_in[3];
  const float* bhh_l0 = (const float*)d_in[4];
  const float* Wih_l0r = (const float*)d_in[5];
  const float* Whh_l0r = (const float*)d_in[6];
  const float* bih_l0r = (const float*)d_in[7];
  const float* bhh_l0r = (const float*)d_in[8];
  const float* Wih_l1 = (const float*)d_in[9];
  const float* Whh_l1 = (const float*)d_in[10];
  const float* bih_l1 = (const float*)d_in[11];
  const float* bhh_l1 = (const float*)d_in[12];
  const float* Wih_l1r = (const float*)d_in[13];
  // d_in[14] = W_hh_l1r unused (reverse h0 = 0)
  const float* bih_l1r = (const float*)d_in[15];
  const float* bhh_l1r = (const float*)d_in[16];
  const float* fc1w = (const float*)d_in[17];
  const float* fc1b = (const float*)d_in[18];
  const float* fc2w = (const float*)d_in[19];
  const float* fc2b = (const float*)d_in[20];
  float* out = (float*)d_out;

  char* ws = (char*)d_ws;
  const size_t M = (size_t)Bsz * Tsz;        // 131072
  const size_t XFB = M * Isz * 2;            // 16.8 MB  x in f16
  const size_t HSB = M * 256 * 2;            // 67.1 MB  hs in f16
  const size_t HFB = (size_t)Bsz * Hsz * 4;  // 131 KB   fallback hfinal
  const size_t XGB = (size_t)64 * Tsz * 8 * 16 * 16 * 2;  // 134 MB l1 xg f16
  const size_t need_min = XFB + HSB + HFB;
  const size_t need_full = need_min + XGB;
  if (ws_size < need_min) return;
  const bool fast = ws_size >= need_full;

  size_t off = 0;
  f16* xf = (f16*)(ws + off); off += XFB;
  f16* hsb = (f16*)(ws + off); off += HSB;
  float* hfinal = (float*)(ws + off); off += HFB;
  f16* xgb = fast ? (f16*)(ws + off) : nullptr;

  const int n4 = (int)(M * Isz / 4);
  cvt_f32_f16<<<dim3((n4 + 255) / 256), dim3(256), 0, stream>>>(x, xf, n4);

  lstm_scan_l0<<<dim3(128), dim3(512), 0, stream>>>(
      xf, Wih_l0, Whh_l0, bih_l0, bhh_l0, Wih_l0r, Whh_l0r, bih_l0r, bhh_l0r, hsb);

  if (fast) {
    xg_gemm_l1<<<dim3(256), dim3(512), 0, stream>>>(hsb, Wih_l1, bih_l1, bhh_l1, xgb);
    lstm_scan_l1x<<<dim3(64), dim3(512), 0, stream>>>(
        xgb, Whh_l1, hsb, Wih_l1r, bih_l1r, bhh_l1r, fc1w, fc1b, fc2w, fc2b, out);
  } else {
    lstm_scan_l1_fb<<<dim3(16), dim3(512), 0, stream>>>(
        hsb, Wih_l1, Whh_l1, bih_l1, bhh_l1, hfinal);
    tail_kernel<<<dim3(256), dim3(512), 0, stream>>>(
        hsb, hfinal, Wih_l1r, bih_l1r, bhh_l1r, fc1w, fc1b, fc2w, fc2b, out);
  }
}